// Round 4
// baseline (660.120 us; speedup 1.0000x reference)
//
#include <hip/hip_runtime.h>
#include <hip/hip_bf16.h>

#define Hd 128
#define Nn 50000
#define Ee 400000
#define Bb 2
#define NROWS 100000          // B*N flat node rows

typedef __attribute__((ext_vector_type(8))) short bf16x8;
typedef __attribute__((ext_vector_type(4))) short bf16x4;
typedef __attribute__((ext_vector_type(4))) float f32x4;

static __device__ __forceinline__ short f2bf(float f) {
    __hip_bfloat16 h = __float2bfloat16(f);
    return *reinterpret_cast<short*>(&h);
}
static __device__ __forceinline__ float bf2f(short s) {
    union { unsigned u; float f; } v; v.u = ((unsigned)(unsigned short)s) << 16;
    return v.f;
}
static __device__ __forceinline__ bf16x8 cvt8(float4 a, float4 b) {
    bf16x8 r;
    r[0] = f2bf(a.x); r[1] = f2bf(a.y); r[2] = f2bf(a.z); r[3] = f2bf(a.w);
    r[4] = f2bf(b.x); r[5] = f2bf(b.y); r[6] = f2bf(b.z); r[7] = f2bf(b.w);
    return r;
}
static __device__ __forceinline__ unsigned pk2(float a, float b) {
    return (unsigned)(unsigned short)f2bf(a) | ((unsigned)(unsigned short)f2bf(b) << 16);
}

// wbuf layout (shorts): WabT[256][128] @0 | W1cT[128][128] @32768 | W2T[128][128] @49152
//                       Wn1T[128][256] @65536 | Wn2T[128][128] @98304   (total 114688)
__global__ void prep_weights(const float* __restrict__ We1, const float* __restrict__ We2,
                             const float* __restrict__ Wn1, const float* __restrict__ Wn2,
                             short* __restrict__ wbuf) {
    int gid = blockIdx.x * 256 + threadIdx.x;
    if (gid < 32768) {                       // WabT: c<128 -> We1[k][c] (src part); else We1[k+128][c-128]
        int c = gid >> 7, k = gid & 127;
        float v = (c < 128) ? We1[k * 128 + c] : We1[(k + 128) * 128 + (c - 128)];
        wbuf[gid] = f2bf(v); return;
    }
    int g = gid - 32768;
    if (g < 16384) { int c = g >> 7, k = g & 127; wbuf[gid] = f2bf(We1[(k + 256) * 128 + c]); return; }
    g -= 16384;
    if (g < 16384) { int c = g >> 7, k = g & 127; wbuf[gid] = f2bf(We2[k * 128 + c]); return; }
    g -= 16384;
    if (g < 32768) { int c = g >> 8, k = g & 255; wbuf[gid] = f2bf(Wn1[k * 128 + c]); return; }
    g -= 32768;
    if (g < 16384) { int c = g >> 7, k = g & 127; wbuf[gid] = f2bf(Wn2[k * 128 + c]); }
}

// ---- CSR by dest ----
__global__ void hist_kernel(const int* __restrict__ ei, int* __restrict__ cnt) {
    int t = blockIdx.x * 256 + threadIdx.x;
    if (t < Ee) atomicAdd(&cnt[ei[Ee + t]], 1);
}
__global__ void scan1(const int* __restrict__ cnt, int* __restrict__ cur, int* __restrict__ part) {
    __shared__ int s[256];
    int i = blockIdx.x * 256 + threadIdx.x;
    int v = (i < Nn) ? cnt[i] : 0;
    s[threadIdx.x] = v; __syncthreads();
    #pragma unroll
    for (int off = 1; off < 256; off <<= 1) {
        int u = (threadIdx.x >= off) ? s[threadIdx.x - off] : 0;
        __syncthreads(); s[threadIdx.x] += u; __syncthreads();
    }
    if (i < Nn) cur[i] = s[threadIdx.x] - v;
    if (threadIdx.x == 255) part[blockIdx.x] = s[255];
}
__global__ void scan2(int* __restrict__ part) {
    if (threadIdx.x == 0 && blockIdx.x == 0) {
        int run = 0;
        for (int i = 0; i < 196; i++) { int t = part[i]; part[i] = run; run += t; }
    }
}
__global__ void scan3(int* __restrict__ cur, const int* __restrict__ part, int* __restrict__ rp) {
    int i = blockIdx.x * 256 + threadIdx.x;
    if (i < Nn) { int v = cur[i] + part[blockIdx.x]; cur[i] = v; rp[i] = v; }
    if (i == 0 && blockIdx.x == 0) rp[Nn] = Ee;
}
__global__ void scatter_k(const int* __restrict__ ei, int* __restrict__ cur, int* __restrict__ elist) {
    int t = blockIdx.x * 256 + threadIdx.x;
    if (t < Ee) { int d = ei[Ee + t]; int pos = atomicAdd(&cur[d], 1); elist[pos] = t; }
}

// ---- node_pre: xa = x@W1a, xb = x@W1b (bf16 out, no bias). Swapped-operand MFMA, direct 8B stores. ----
__global__ __launch_bounds__(256) void node_pre(
    const float* __restrict__ x, const short* __restrict__ WabT,
    short* __restrict__ xa, short* __restrict__ xb)
{
    __shared__ __align__(16) short X[32 * 128];     // [32 rows][16 groups of 16B], XOR-swizzled

    const int nbase = blockIdx.x * 32;              // 100000 % 32 == 0 -> no guards
    const int t = threadIdx.x;
    const int wv = t >> 6, lane = t & 63;
    const int row16 = lane & 15, kg = lane >> 4;

    // stage x tile
    {
        int g = t >> 3, q = t & 7;
        const float* src = x + ((size_t)(nbase + g)) * Hd + q * 16;
        float4 a0 = ((const float4*)src)[0], a1 = ((const float4*)src)[1];
        float4 a2 = ((const float4*)src)[2], a3 = ((const float4*)src)[3];
        ((bf16x8*)X)[g * 16 + ((q * 2) ^ (g & 7))]     = cvt8(a0, a1);
        ((bf16x8*)X)[g * 16 + ((q * 2 + 1) ^ (g & 7))] = cvt8(a2, a3);
    }

    bf16x8 wf[4][4];                                 // wave covers out-ch [wv*64, wv*64+64)
    #pragma unroll
    for (int nt = 0; nt < 4; nt++) {
        int n = wv * 64 + nt * 16 + row16;
        #pragma unroll
        for (int kt = 0; kt < 4; kt++)
            wf[kt][nt] = *(const bf16x8*)(WabT + n * 128 + kt * 32 + kg * 8);
    }
    __syncthreads();

    f32x4 acc[2][4];
    #pragma unroll
    for (int mt = 0; mt < 2; mt++)
        #pragma unroll
        for (int nt = 0; nt < 4; nt++) acc[mt][nt] = (f32x4){0.f,0.f,0.f,0.f};

    #pragma unroll
    for (int mt = 0; mt < 2; mt++) {
        int row = mt * 16 + row16;
        #pragma unroll
        for (int kt = 0; kt < 4; kt++) {
            bf16x8 xf = ((const bf16x8*)X)[row * 16 + ((kt * 4 + kg) ^ (row & 7))];
            #pragma unroll
            for (int nt = 0; nt < 4; nt++)
                acc[mt][nt] = __builtin_amdgcn_mfma_f32_16x16x32_bf16(wf[kt][nt], xf, acc[mt][nt], 0, 0, 0);
        }
    }

    // direct stores: lane holds 4 consecutive out-channels of node row16 (per mt,nt)
    #pragma unroll
    for (int mt = 0; mt < 2; mt++) {
        size_t node = nbase + mt * 16 + row16;
        #pragma unroll
        for (int nt = 0; nt < 4; nt++) {
            int ch = wv * 64 + nt * 16 + kg * 4;
            uint2 pk = { pk2(acc[mt][nt][0], acc[mt][nt][1]), pk2(acc[mt][nt][2], acc[mt][nt][3]) };
            short* dst = (ch < 128) ? (xa + node * Hd + ch) : (xb + node * Hd + (ch - 128));
            *(uint2*)dst = pk;
        }
    }
}

// ---- edge_mlp: e = relu(ea@W1c + xa[src] + xb[dest] + be1) @ W2 + be2 ----
// Swapped-operand MFMA: ea loaded straight from global (no LDS), h in one 16KB LDS tile,
// xa/xb as per-lane 8B gathers (L3-hot), e stored direct from registers. ONE barrier.
__global__ __launch_bounds__(256, 4) void edge_mlp(
    const float* __restrict__ ea, const int* __restrict__ ei,
    const short* __restrict__ xa, const short* __restrict__ xb,
    const short* __restrict__ W1cT, const float* __restrict__ be1,
    const short* __restrict__ W2T, const float* __restrict__ be2,
    float* __restrict__ e_out)
{
    __shared__ __align__(16) short A2[64 * 128];    // [edge][ch], 16B-group XOR-swizzled

    const int bid = blockIdx.x;
    const int b = bid / (Ee / 64);
    const int ebase = (bid % (Ee / 64)) * 64;
    const int t = threadIdx.x;
    const int wv = t >> 6, lane = t & 63;
    const int row16 = lane & 15, kg = lane >> 4;

    bf16x8 w1[4][2];                                 // wave covers ch [wv*32, wv*32+32)
    #pragma unroll
    for (int c = 0; c < 2; c++) {
        int n = wv * 32 + c * 16 + row16;
        #pragma unroll
        for (int kt = 0; kt < 4; kt++)
            w1[kt][c] = *(const bf16x8*)(W1cT + n * 128 + kt * 32 + kg * 8);
    }

    f32x4 acc[4][2];
    #pragma unroll
    for (int mt = 0; mt < 4; mt++) { acc[mt][0] = (f32x4){0.f,0.f,0.f,0.f}; acc[mt][1] = (f32x4){0.f,0.f,0.f,0.f}; }

    // L1: B-frag = 8 consecutive k of the edge's own ea row -> direct global load
    const float* eab = ea + ((size_t)b * Ee + ebase) * Hd;
    #pragma unroll
    for (int mt = 0; mt < 4; mt++) {
        const float* rowp = eab + (mt * 16 + row16) * Hd + kg * 8;
        #pragma unroll
        for (int kt = 0; kt < 4; kt++) {
            float4 a0 = *(const float4*)(rowp + kt * 32);
            float4 a1 = *(const float4*)(rowp + kt * 32 + 4);
            bf16x8 af = cvt8(a0, a1);
            acc[mt][0] = __builtin_amdgcn_mfma_f32_16x16x32_bf16(w1[kt][0], af, acc[mt][0], 0, 0, 0);
            acc[mt][1] = __builtin_amdgcn_mfma_f32_16x16x32_bf16(w1[kt][1], af, acc[mt][1], 0, 0, 0);
        }
    }

    float4 b1v[2];
    b1v[0] = *(const float4*)(be1 + wv * 32 + kg * 4);
    b1v[1] = *(const float4*)(be1 + wv * 32 + 16 + kg * 4);

    // epilogue: + bias + xa[src] + xb[dest], relu, pack -> A2
    #pragma unroll
    for (int mt = 0; mt < 4; mt++) {
        int erow = mt * 16 + row16;
        int eidx = ebase + erow;
        int s = ei[eidx], d = ei[Ee + eidx];
        const short* xar = xa + ((size_t)b * Nn + s) * Hd;
        const short* xbr = xb + ((size_t)b * Nn + d) * Hd;
        #pragma unroll
        for (int c = 0; c < 2; c++) {
            int n0 = wv * 32 + c * 16 + kg * 4;
            bf16x4 av = *(const bf16x4*)(xar + n0);
            bf16x4 bv = *(const bf16x4*)(xbr + n0);
            float v[4];
            #pragma unroll
            for (int r = 0; r < 4; r++) {
                float u = acc[mt][c][r] + b1v[c][r] + bf2f(av[r]) + bf2f(bv[r]);
                v[r] = u > 0.f ? u : 0.f;
            }
            int G = (n0 >> 3) ^ (erow & 7);
            *(uint2*)((char*)A2 + erow * 256 + G * 16 + (n0 & 7) * 2) = (uint2){ pk2(v[0], v[1]), pk2(v[2], v[3]) };
        }
    }

    bf16x8 w2[4][2];
    #pragma unroll
    for (int c = 0; c < 2; c++) {
        int n = wv * 32 + c * 16 + row16;
        #pragma unroll
        for (int kt = 0; kt < 4; kt++)
            w2[kt][c] = *(const bf16x8*)(W2T + n * 128 + kt * 32 + kg * 8);
    }
    __syncthreads();

    // L2 from A2, direct e stores
    f32x4 acc2[4][2];
    #pragma unroll
    for (int mt = 0; mt < 4; mt++) { acc2[mt][0] = (f32x4){0.f,0.f,0.f,0.f}; acc2[mt][1] = (f32x4){0.f,0.f,0.f,0.f}; }
    #pragma unroll
    for (int mt = 0; mt < 4; mt++) {
        int erow = mt * 16 + row16;
        #pragma unroll
        for (int kt = 0; kt < 4; kt++) {
            bf16x8 hf = *(const bf16x8*)((const char*)A2 + erow * 256 + (((kt * 4 + kg) ^ (erow & 7)) * 16));
            acc2[mt][0] = __builtin_amdgcn_mfma_f32_16x16x32_bf16(w2[kt][0], hf, acc2[mt][0], 0, 0, 0);
            acc2[mt][1] = __builtin_amdgcn_mfma_f32_16x16x32_bf16(w2[kt][1], hf, acc2[mt][1], 0, 0, 0);
        }
    }

    float4 b2v[2];
    b2v[0] = *(const float4*)(be2 + wv * 32 + kg * 4);
    b2v[1] = *(const float4*)(be2 + wv * 32 + 16 + kg * 4);

    float* eo = e_out + ((size_t)b * Ee + ebase) * Hd;
    #pragma unroll
    for (int mt = 0; mt < 4; mt++) {
        int erow = mt * 16 + row16;
        #pragma unroll
        for (int c = 0; c < 2; c++) {
            int n0 = wv * 32 + c * 16 + kg * 4;
            float4 ov;
            ov.x = acc2[mt][c][0] + b2v[c].x;
            ov.y = acc2[mt][c][1] + b2v[c].y;
            ov.z = acc2[mt][c][2] + b2v[c].z;
            ov.w = acc2[mt][c][3] + b2v[c].w;
            *(float4*)(eo + (size_t)erow * Hd + n0) = ov;
        }
    }
}

// ---- node_mlp: CSR-gather agg from e, x_out = relu(concat(x,agg)@Wn1+bn1)@Wn2+bn2 ----
__global__ __launch_bounds__(256) void node_mlp(
    const float* __restrict__ x, const float* __restrict__ e_out,
    const int* __restrict__ rp, const int* __restrict__ elist,
    const short* __restrict__ Wn1T, const float* __restrict__ bn1,
    const short* __restrict__ Wn2T, const float* __restrict__ bn2,
    float* __restrict__ xout)
{
    __shared__ __align__(16) short A[32 * 256];      // [32 rows][32 groups] (x | agg), swizzled
    __shared__ __align__(16) short A2[32 * 128];     // [32 rows][16 groups] hidden

    const int tilesPerB = (Nn + 31) / 32;            // 1563
    const int bid = blockIdx.x;
    const int b = bid / tilesPerB;
    const int nbase = (bid % tilesPerB) * 32;
    const int t = threadIdx.x;
    const int wv = t >> 6, lane = t & 63;
    const int row16 = lane & 15, kg = lane >> 4;

    // gather + stage (8 threads per node, 16 cols each)
    {
        int g = t >> 3, q = t & 7;
        int n = nbase + g;
        float4 xv0 = {0,0,0,0}, xv1 = xv0, xv2 = xv0, xv3 = xv0;
        float4 s0 = {0,0,0,0}, s1 = s0, s2 = s0, s3 = s0;
        if (n < Nn) {
            const float* xr = x + ((size_t)b * Nn + n) * Hd + q * 16;
            xv0 = ((const float4*)xr)[0]; xv1 = ((const float4*)xr)[1];
            xv2 = ((const float4*)xr)[2]; xv3 = ((const float4*)xr)[3];
            int jb = rp[n], je = rp[n + 1];
            const float* eb = e_out + (size_t)b * Ee * Hd + q * 16;
            int j = jb;
            for (; j + 2 <= je; j += 2) {
                int e0 = elist[j], e1 = elist[j + 1];
                const float* p0 = eb + (size_t)e0 * Hd;
                const float* p1 = eb + (size_t)e1 * Hd;
                float4 u0 = ((const float4*)p0)[0], u1 = ((const float4*)p0)[1];
                float4 u2 = ((const float4*)p0)[2], u3 = ((const float4*)p0)[3];
                float4 w0 = ((const float4*)p1)[0], w1_ = ((const float4*)p1)[1];
                float4 w2_ = ((const float4*)p1)[2], w3 = ((const float4*)p1)[3];
                s0.x += u0.x + w0.x; s0.y += u0.y + w0.y; s0.z += u0.z + w0.z; s0.w += u0.w + w0.w;
                s1.x += u1.x + w1_.x; s1.y += u1.y + w1_.y; s1.z += u1.z + w1_.z; s1.w += u1.w + w1_.w;
                s2.x += u2.x + w2_.x; s2.y += u2.y + w2_.y; s2.z += u2.z + w2_.z; s2.w += u2.w + w2_.w;
                s3.x += u3.x + w3.x; s3.y += u3.y + w3.y; s3.z += u3.z + w3.z; s3.w += u3.w + w3.w;
            }
            if (j < je) {
                const float* p0 = eb + (size_t)elist[j] * Hd;
                float4 u0 = ((const float4*)p0)[0], u1 = ((const float4*)p0)[1];
                float4 u2 = ((const float4*)p0)[2], u3 = ((const float4*)p0)[3];
                s0.x += u0.x; s0.y += u0.y; s0.z += u0.z; s0.w += u0.w;
                s1.x += u1.x; s1.y += u1.y; s1.z += u1.z; s1.w += u1.w;
                s2.x += u2.x; s2.y += u2.y; s2.z += u2.z; s2.w += u2.w;
                s3.x += u3.x; s3.y += u3.y; s3.z += u3.z; s3.w += u3.w;
            }
        }
        ((bf16x8*)A)[g * 32 + ((q * 2) ^ (g & 7))]          = cvt8(xv0, xv1);
        ((bf16x8*)A)[g * 32 + ((q * 2 + 1) ^ (g & 7))]      = cvt8(xv2, xv3);
        ((bf16x8*)A)[g * 32 + ((16 + q * 2) ^ (g & 7))]     = cvt8(s0, s1);
        ((bf16x8*)A)[g * 32 + ((16 + q * 2 + 1) ^ (g & 7))] = cvt8(s2, s3);
    }

    bf16x8 w1[8][2];
    #pragma unroll
    for (int c = 0; c < 2; c++) {
        int n = wv * 32 + c * 16 + row16;
        #pragma unroll
        for (int kt = 0; kt < 8; kt++)
            w1[kt][c] = *(const bf16x8*)(Wn1T + n * 256 + kt * 32 + kg * 8);
    }
    __syncthreads();

    // L1 GEMM K=256
    f32x4 acc[2][2];
    #pragma unroll
    for (int mt = 0; mt < 2; mt++) { acc[mt][0] = (f32x4){0.f,0.f,0.f,0.f}; acc[mt][1] = (f32x4){0.f,0.f,0.f,0.f}; }
    #pragma unroll
    for (int mt = 0; mt < 2; mt++) {
        int row = mt * 16 + row16;
        #pragma unroll
        for (int kt = 0; kt < 8; kt++) {
            bf16x8 af = ((const bf16x8*)A)[row * 32 + ((kt * 4 + kg) ^ (row & 7))];
            acc[mt][0] = __builtin_amdgcn_mfma_f32_16x16x32_bf16(w1[kt][0], af, acc[mt][0], 0, 0, 0);
            acc[mt][1] = __builtin_amdgcn_mfma_f32_16x16x32_bf16(w1[kt][1], af, acc[mt][1], 0, 0, 0);
        }
    }

    float4 b1v[2];
    b1v[0] = *(const float4*)(bn1 + wv * 32 + kg * 4);
    b1v[1] = *(const float4*)(bn1 + wv * 32 + 16 + kg * 4);

    #pragma unroll
    for (int mt = 0; mt < 2; mt++) {
        int row = mt * 16 + row16;
        #pragma unroll
        for (int c = 0; c < 2; c++) {
            int n0 = wv * 32 + c * 16 + kg * 4;
            float v[4];
            #pragma unroll
            for (int r = 0; r < 4; r++) {
                float u = acc[mt][c][r] + b1v[c][r];
                v[r] = u > 0.f ? u : 0.f;
            }
            int G = (n0 >> 3) ^ (row & 7);
            *(uint2*)((char*)A2 + row * 256 + G * 16 + (n0 & 7) * 2) = (uint2){ pk2(v[0], v[1]), pk2(v[2], v[3]) };
        }
    }

    bf16x8 w2[4][2];
    #pragma unroll
    for (int c = 0; c < 2; c++) {
        int n = wv * 32 + c * 16 + row16;
        #pragma unroll
        for (int kt = 0; kt < 4; kt++)
            w2[kt][c] = *(const bf16x8*)(Wn2T + n * 128 + kt * 32 + kg * 8);
    }
    __syncthreads();

    // L2 GEMM K=128, direct stores
    f32x4 acc2[2][2];
    #pragma unroll
    for (int mt = 0; mt < 2; mt++) { acc2[mt][0] = (f32x4){0.f,0.f,0.f,0.f}; acc2[mt][1] = (f32x4){0.f,0.f,0.f,0.f}; }
    #pragma unroll
    for (int mt = 0; mt < 2; mt++) {
        int row = mt * 16 + row16;
        #pragma unroll
        for (int kt = 0; kt < 4; kt++) {
            bf16x8 hf = *(const bf16x8*)((const char*)A2 + row * 256 + (((kt * 4 + kg) ^ (row & 7)) * 16));
            acc2[mt][0] = __builtin_amdgcn_mfma_f32_16x16x32_bf16(w2[kt][0], hf, acc2[mt][0], 0, 0, 0);
            acc2[mt][1] = __builtin_amdgcn_mfma_f32_16x16x32_bf16(w2[kt][1], hf, acc2[mt][1], 0, 0, 0);
        }
    }

    float4 b2v[2];
    b2v[0] = *(const float4*)(bn2 + wv * 32 + kg * 4);
    b2v[1] = *(const float4*)(bn2 + wv * 32 + 16 + kg * 4);

    #pragma unroll
    for (int mt = 0; mt < 2; mt++) {
        int node = nbase + mt * 16 + row16;
        if (node < Nn) {
            #pragma unroll
            for (int c = 0; c < 2; c++) {
                int n0 = wv * 32 + c * 16 + kg * 4;
                float4 ov;
                ov.x = acc2[mt][c][0] + b2v[c].x;
                ov.y = acc2[mt][c][1] + b2v[c].y;
                ov.z = acc2[mt][c][2] + b2v[c].z;
                ov.w = acc2[mt][c][3] + b2v[c].w;
                *(float4*)(xout + ((size_t)b * Nn + node) * Hd + n0) = ov;
            }
        }
    }
}

extern "C" void kernel_launch(void* const* d_in, const int* in_sizes, int n_in,
                              void* d_out, int out_size, void* d_ws, size_t ws_size,
                              hipStream_t stream) {
    const float* x   = (const float*)d_in[0];
    const int*   ei  = (const int*)d_in[1];
    const float* ea  = (const float*)d_in[2];
    const float* We1 = (const float*)d_in[3];
    const float* be1 = (const float*)d_in[4];
    const float* We2 = (const float*)d_in[5];
    const float* be2 = (const float*)d_in[6];
    const float* Wn1 = (const float*)d_in[7];
    const float* bn1 = (const float*)d_in[8];
    const float* Wn2 = (const float*)d_in[9];
    const float* bn2 = (const float*)d_in[10];

    float* xout  = (float*)d_out;
    float* e_out = xout + (size_t)Bb * Nn * Hd;     // outputs: x_out, then e

    short* wbuf  = (short*)d_ws;                    // 114688 shorts
    short* xa    = wbuf + 114688;                   // NROWS*128 bf16
    short* xb    = xa + (size_t)NROWS * Hd;
    int*   cnt   = (int*)(xb + (size_t)NROWS * Hd);
    int*   cur   = cnt + Nn;
    int*   rp    = cur + Nn;                        // Nn+1
    int*   part  = rp + Nn + 1;                     // 256
    int*   elist = part + 256;                      // Ee

    hipMemsetAsync(cnt, 0, Nn * sizeof(int), stream);
    prep_weights<<<448, 256, 0, stream>>>(We1, We2, Wn1, Wn2, wbuf);
    hist_kernel<<<(Ee + 255) / 256, 256, 0, stream>>>(ei, cnt);
    scan1<<<196, 256, 0, stream>>>(cnt, cur, part);
    scan2<<<1, 64, 0, stream>>>(part);
    scan3<<<196, 256, 0, stream>>>(cur, part, rp);
    scatter_k<<<(Ee + 255) / 256, 256, 0, stream>>>(ei, cur, elist);

    node_pre<<<NROWS / 32, 256, 0, stream>>>(x, wbuf, xa, xb);

    edge_mlp<<<Bb * (Ee / 64), 256, 0, stream>>>(
        ea, ei, xa, xb, wbuf + 32768, be1, wbuf + 49152, be2, e_out);

    node_mlp<<<Bb * ((Nn + 31) / 32), 256, 0, stream>>>(
        x, e_out, rp, elist, wbuf + 65536, bn1, wbuf + 98304, bn2, xout);
}

// Round 5
// 505.303 us; speedup vs baseline: 1.3064x; 1.3064x over previous
//
#include <hip/hip_runtime.h>
#include <hip/hip_bf16.h>

#define Hd 128
#define Nn 50000
#define Ee 400000
#define Bb 2
#define NROWS 100000          // B*N flat node rows

typedef __attribute__((ext_vector_type(8))) short bf16x8;
typedef __attribute__((ext_vector_type(4))) short bf16x4;
typedef __attribute__((ext_vector_type(4))) float f32x4;

static __device__ __forceinline__ short f2bf(float f) {
    __hip_bfloat16 h = __float2bfloat16(f);
    return *reinterpret_cast<short*>(&h);
}
static __device__ __forceinline__ float bf2f(short s) {
    union { unsigned u; float f; } v; v.u = ((unsigned)(unsigned short)s) << 16;
    return v.f;
}
static __device__ __forceinline__ bf16x8 cvt8(float4 a, float4 b) {
    bf16x8 r;
    r[0] = f2bf(a.x); r[1] = f2bf(a.y); r[2] = f2bf(a.z); r[3] = f2bf(a.w);
    r[4] = f2bf(b.x); r[5] = f2bf(b.y); r[6] = f2bf(b.z); r[7] = f2bf(b.w);
    return r;
}
static __device__ __forceinline__ unsigned pk2(float a, float b) {
    return (unsigned)(unsigned short)f2bf(a) | ((unsigned)(unsigned short)f2bf(b) << 16);
}

// wbuf layout (shorts): WabT[256][128] @0 | W1cT[128][128] @32768 | W2T[128][128] @49152
//                       Wn1T[128][256] @65536 | Wn2T[128][128] @98304   (total 114688)
__global__ void prep_weights(const float* __restrict__ We1, const float* __restrict__ We2,
                             const float* __restrict__ Wn1, const float* __restrict__ Wn2,
                             short* __restrict__ wbuf) {
    int gid = blockIdx.x * 256 + threadIdx.x;
    if (gid < 32768) {
        int c = gid >> 7, k = gid & 127;
        float v = (c < 128) ? We1[k * 128 + c] : We1[(k + 128) * 128 + (c - 128)];
        wbuf[gid] = f2bf(v); return;
    }
    int g = gid - 32768;
    if (g < 16384) { int c = g >> 7, k = g & 127; wbuf[gid] = f2bf(We1[(k + 256) * 128 + c]); return; }
    g -= 16384;
    if (g < 16384) { int c = g >> 7, k = g & 127; wbuf[gid] = f2bf(We2[k * 128 + c]); return; }
    g -= 16384;
    if (g < 32768) { int c = g >> 8, k = g & 255; wbuf[gid] = f2bf(Wn1[k * 128 + c]); return; }
    g -= 32768;
    if (g < 16384) { int c = g >> 7, k = g & 127; wbuf[gid] = f2bf(Wn2[k * 128 + c]); }
}

// ---- CSR by dest ----
__global__ void hist_kernel(const int* __restrict__ ei, int* __restrict__ cnt) {
    int t = blockIdx.x * 256 + threadIdx.x;
    if (t < Ee) atomicAdd(&cnt[ei[Ee + t]], 1);
}
__global__ void scan1(const int* __restrict__ cnt, int* __restrict__ cur, int* __restrict__ part) {
    __shared__ int s[256];
    int i = blockIdx.x * 256 + threadIdx.x;
    int v = (i < Nn) ? cnt[i] : 0;
    s[threadIdx.x] = v; __syncthreads();
    #pragma unroll
    for (int off = 1; off < 256; off <<= 1) {
        int u = (threadIdx.x >= off) ? s[threadIdx.x - off] : 0;
        __syncthreads(); s[threadIdx.x] += u; __syncthreads();
    }
    if (i < Nn) cur[i] = s[threadIdx.x] - v;
    if (threadIdx.x == 255) part[blockIdx.x] = s[255];
}
__global__ void scan2(int* __restrict__ part) {
    if (threadIdx.x == 0 && blockIdx.x == 0) {
        int run = 0;
        for (int i = 0; i < 196; i++) { int t = part[i]; part[i] = run; run += t; }
    }
}
__global__ void scan3(int* __restrict__ cur, const int* __restrict__ part, int* __restrict__ rp) {
    int i = blockIdx.x * 256 + threadIdx.x;
    if (i < Nn) { int v = cur[i] + part[blockIdx.x]; cur[i] = v; rp[i] = v; }
    if (i == 0 && blockIdx.x == 0) rp[Nn] = Ee;
}
__global__ void scatter_k(const int* __restrict__ ei, int* __restrict__ cur, int* __restrict__ elist) {
    int t = blockIdx.x * 256 + threadIdx.x;
    if (t < Ee) { int d = ei[Ee + t]; int pos = atomicAdd(&cur[d], 1); elist[pos] = t; }
}

// ---- node_pre: xa = x@W1a, xb = x@W1b (bf16 out, no bias) ----
__global__ __launch_bounds__(256) void node_pre(
    const float* __restrict__ x, const short* __restrict__ WabT,
    short* __restrict__ xa, short* __restrict__ xb)
{
    __shared__ __align__(16) short X[32 * 128];

    const int nbase = blockIdx.x * 32;
    const int t = threadIdx.x;
    const int wv = t >> 6, lane = t & 63;
    const int row16 = lane & 15, kg = lane >> 4;

    {
        int g = t >> 3, q = t & 7;
        const float* src = x + ((size_t)(nbase + g)) * Hd + q * 16;
        float4 a0 = ((const float4*)src)[0], a1 = ((const float4*)src)[1];
        float4 a2 = ((const float4*)src)[2], a3 = ((const float4*)src)[3];
        ((bf16x8*)X)[g * 16 + ((q * 2) ^ (g & 7))]     = cvt8(a0, a1);
        ((bf16x8*)X)[g * 16 + ((q * 2 + 1) ^ (g & 7))] = cvt8(a2, a3);
    }

    bf16x8 wf[4][4];
    #pragma unroll
    for (int nt = 0; nt < 4; nt++) {
        int n = wv * 64 + nt * 16 + row16;
        #pragma unroll
        for (int kt = 0; kt < 4; kt++)
            wf[kt][nt] = *(const bf16x8*)(WabT + n * 128 + kt * 32 + kg * 8);
    }
    __syncthreads();

    f32x4 acc[2][4];
    #pragma unroll
    for (int mt = 0; mt < 2; mt++)
        #pragma unroll
        for (int nt = 0; nt < 4; nt++) acc[mt][nt] = (f32x4){0.f,0.f,0.f,0.f};

    #pragma unroll
    for (int mt = 0; mt < 2; mt++) {
        int row = mt * 16 + row16;
        #pragma unroll
        for (int kt = 0; kt < 4; kt++) {
            bf16x8 xf = ((const bf16x8*)X)[row * 16 + ((kt * 4 + kg) ^ (row & 7))];
            #pragma unroll
            for (int nt = 0; nt < 4; nt++)
                acc[mt][nt] = __builtin_amdgcn_mfma_f32_16x16x32_bf16(wf[kt][nt], xf, acc[mt][nt], 0, 0, 0);
        }
    }

    #pragma unroll
    for (int mt = 0; mt < 2; mt++) {
        size_t node = nbase + mt * 16 + row16;
        #pragma unroll
        for (int nt = 0; nt < 4; nt++) {
            int ch = wv * 64 + nt * 16 + kg * 4;
            uint2 pk = { pk2(acc[mt][nt][0], acc[mt][nt][1]), pk2(acc[mt][nt][2], acc[mt][nt][3]) };
            short* dst = (ch < 128) ? (xa + node * Hd + ch) : (xb + node * Hd + (ch - 128));
            *(uint2*)dst = pk;
        }
    }
}

// ---- edge_mlp: e = relu(ea@W1c + xa[src] + xb[dest] + be1) @ W2 + be2 ----
// 512 thr / 8 waves x 16 cols: tiny per-wave state (w[4]=16 VGPR, acc[4]=16 VGPR).
// Coalesced ea->LDS staging, swapped-operand MFMA, in-register epilogue, direct e stores.
__global__ __launch_bounds__(512, 4) void edge_mlp(
    const float* __restrict__ ea, const int* __restrict__ ei,
    const short* __restrict__ xa, const short* __restrict__ xb,
    const short* __restrict__ W1cT, const float* __restrict__ be1,
    const short* __restrict__ W2T, const float* __restrict__ be2,
    float* __restrict__ e_out)
{
    __shared__ __align__(16) short Aea[64 * 128];   // 16KB, 16B-group XOR-swizzled
    __shared__ __align__(16) short A2[64 * 128];    // 16KB hidden

    const int bid = blockIdx.x;
    const int b = bid / (Ee / 64);
    const int ebase = (bid % (Ee / 64)) * 64;
    const int t = threadIdx.x;
    const int wv = t >> 6, lane = t & 63;
    const int row16 = lane & 15, kg = lane >> 4;
    const int n0 = wv * 16 + kg * 4;                // this lane's 4 output channels

    // stage ea tile: 512 thr x 64B contiguous each, fully coalesced
    {
        int row = t >> 3, q = t & 7;
        const float* src = ea + ((size_t)b * Ee + ebase + row) * Hd + q * 16;
        float4 a0 = ((const float4*)src)[0], a1 = ((const float4*)src)[1];
        float4 a2 = ((const float4*)src)[2], a3 = ((const float4*)src)[3];
        ((bf16x8*)Aea)[row * 16 + ((q * 2) ^ (row & 7))]     = cvt8(a0, a1);
        ((bf16x8*)Aea)[row * 16 + ((q * 2 + 1) ^ (row & 7))] = cvt8(a2, a3);
    }

    // weights for this wave's 16 cols (16 VGPR)
    bf16x8 w1[4];
    {
        const short* wp = W1cT + (wv * 16 + row16) * 128 + kg * 8;
        #pragma unroll
        for (int kt = 0; kt < 4; kt++) w1[kt] = *(const bf16x8*)(wp + kt * 32);
    }
    // prefetch edge endpoints (overlaps staging latency)
    int sn[4], dn[4];
    #pragma unroll
    for (int mt = 0; mt < 4; mt++) {
        int eidx = ebase + mt * 16 + row16;
        sn[mt] = ei[eidx]; dn[mt] = ei[Ee + eidx];
    }
    __syncthreads();

    // L1 GEMM: acc[mt] = 4 channels (n0..n0+3) of edge (mt*16+row16)
    f32x4 acc[4];
    #pragma unroll
    for (int mt = 0; mt < 4; mt++) acc[mt] = (f32x4){0.f,0.f,0.f,0.f};
    #pragma unroll
    for (int kt = 0; kt < 4; kt++) {
        #pragma unroll
        for (int mt = 0; mt < 4; mt++) {
            int row = mt * 16 + row16;
            bf16x8 af = ((const bf16x8*)Aea)[row * 16 + ((kt * 4 + kg) ^ (row & 7))];
            acc[mt] = __builtin_amdgcn_mfma_f32_16x16x32_bf16(w1[kt], af, acc[mt], 0, 0, 0);
        }
    }

    // issue all xa/xb gathers together (L3-hot, 8B each)
    bf16x4 av[4], bv[4];
    #pragma unroll
    for (int mt = 0; mt < 4; mt++) {
        av[mt] = *(const bf16x4*)(xa + ((size_t)b * Nn + sn[mt]) * Hd + n0);
        bv[mt] = *(const bf16x4*)(xb + ((size_t)b * Nn + dn[mt]) * Hd + n0);
    }
    float4 b1v = *(const float4*)(be1 + n0);

    bf16x8 w2[4];
    {
        const short* wp = W2T + (wv * 16 + row16) * 128 + kg * 8;
        #pragma unroll
        for (int kt = 0; kt < 4; kt++) w2[kt] = *(const bf16x8*)(wp + kt * 32);
    }

    // epilogue: bias + skip-adds + relu -> A2 (8B swizzled writes)
    #pragma unroll
    for (int mt = 0; mt < 4; mt++) {
        int row = mt * 16 + row16;
        float v[4];
        #pragma unroll
        for (int r = 0; r < 4; r++) {
            float u = acc[mt][r] + b1v[r] + bf2f(av[mt][r]) + bf2f(bv[mt][r]);
            v[r] = u > 0.f ? u : 0.f;
        }
        int G = (n0 >> 3) ^ (row & 7);
        *(uint2*)((char*)A2 + row * 256 + G * 16 + (n0 & 7) * 2) = (uint2){ pk2(v[0], v[1]), pk2(v[2], v[3]) };
    }
    __syncthreads();

    // L2 GEMM, direct e stores
    f32x4 acc2[4];
    #pragma unroll
    for (int mt = 0; mt < 4; mt++) acc2[mt] = (f32x4){0.f,0.f,0.f,0.f};
    #pragma unroll
    for (int kt = 0; kt < 4; kt++) {
        #pragma unroll
        for (int mt = 0; mt < 4; mt++) {
            int row = mt * 16 + row16;
            bf16x8 hf = *(const bf16x8*)((const char*)A2 + row * 256 + (((kt * 4 + kg) ^ (row & 7)) * 16));
            acc2[mt] = __builtin_amdgcn_mfma_f32_16x16x32_bf16(w2[kt], hf, acc2[mt], 0, 0, 0);
        }
    }
    float4 b2v = *(const float4*)(be2 + n0);
    float* eo = e_out + ((size_t)b * Ee + ebase) * Hd;
    #pragma unroll
    for (int mt = 0; mt < 4; mt++) {
        float4 ov;
        ov.x = acc2[mt][0] + b2v.x;
        ov.y = acc2[mt][1] + b2v.y;
        ov.z = acc2[mt][2] + b2v.z;
        ov.w = acc2[mt][3] + b2v.w;
        *(float4*)(eo + (size_t)(mt * 16 + row16) * Hd + n0) = ov;
    }
}

// ---- node_mlp: CSR-gather agg from e, x_out = relu(concat(x,agg)@Wn1+bn1)@Wn2+bn2 ----
// 512 thr / 8 waves x 16 cols; 16 threads per node on the gather (4-deep unroll).
__global__ __launch_bounds__(512, 4) void node_mlp(
    const float* __restrict__ x, const float* __restrict__ e_out,
    const int* __restrict__ rp, const int* __restrict__ elist,
    const short* __restrict__ Wn1T, const float* __restrict__ bn1,
    const short* __restrict__ Wn2T, const float* __restrict__ bn2,
    float* __restrict__ xout)
{
    __shared__ __align__(16) short A[32 * 256];      // 16KB: [node][32 groups] (x | agg)
    __shared__ __align__(16) short A2[32 * 128];     // 8KB hidden

    const int tilesPerB = (Nn + 31) / 32;            // 1563
    const int bid = blockIdx.x;
    const int b = bid / tilesPerB;
    const int nbase = (bid % tilesPerB) * 32;
    const int t = threadIdx.x;
    const int wv = t >> 6, lane = t & 63;
    const int row16 = lane & 15, kg = lane >> 4;
    const int n0 = wv * 16 + kg * 4;

    // gather + stage: 16 threads per node, 8 floats (32B) each
    {
        int g = t >> 4, q2 = t & 15;
        int n = nbase + g;
        float4 xv0 = {0,0,0,0}, xv1 = xv0;
        float4 s0 = {0,0,0,0}, s1 = s0;
        if (n < Nn) {
            const float* xr = x + ((size_t)b * Nn + n) * Hd + q2 * 8;
            xv0 = ((const float4*)xr)[0]; xv1 = ((const float4*)xr)[1];
            int jb = rp[n], je = rp[n + 1];
            const float* eb = e_out + (size_t)b * Ee * Hd + q2 * 8;
            int j = jb;
            for (; j + 4 <= je; j += 4) {
                int e0 = elist[j], e1 = elist[j+1], e2 = elist[j+2], e3 = elist[j+3];
                const float* p0 = eb + (size_t)e0 * Hd;
                const float* p1 = eb + (size_t)e1 * Hd;
                const float* p2 = eb + (size_t)e2 * Hd;
                const float* p3 = eb + (size_t)e3 * Hd;
                float4 u0 = ((const float4*)p0)[0], u1 = ((const float4*)p0)[1];
                float4 u2 = ((const float4*)p1)[0], u3 = ((const float4*)p1)[1];
                float4 u4 = ((const float4*)p2)[0], u5 = ((const float4*)p2)[1];
                float4 u6 = ((const float4*)p3)[0], u7 = ((const float4*)p3)[1];
                s0.x += (u0.x + u2.x) + (u4.x + u6.x);
                s0.y += (u0.y + u2.y) + (u4.y + u6.y);
                s0.z += (u0.z + u2.z) + (u4.z + u6.z);
                s0.w += (u0.w + u2.w) + (u4.w + u6.w);
                s1.x += (u1.x + u3.x) + (u5.x + u7.x);
                s1.y += (u1.y + u3.y) + (u5.y + u7.y);
                s1.z += (u1.z + u3.z) + (u5.z + u7.z);
                s1.w += (u1.w + u3.w) + (u5.w + u7.w);
            }
            for (; j < je; j++) {
                const float* p0 = eb + (size_t)elist[j] * Hd;
                float4 u0 = ((const float4*)p0)[0], u1 = ((const float4*)p0)[1];
                s0.x += u0.x; s0.y += u0.y; s0.z += u0.z; s0.w += u0.w;
                s1.x += u1.x; s1.y += u1.y; s1.z += u1.z; s1.w += u1.w;
            }
        }
        ((bf16x8*)A)[g * 32 + (q2 ^ (g & 7))]        = cvt8(xv0, xv1);
        ((bf16x8*)A)[g * 32 + ((16 + q2) ^ (g & 7))] = cvt8(s0, s1);
    }

    bf16x8 w1[8];
    {
        const short* wp = Wn1T + (wv * 16 + row16) * 256 + kg * 8;
        #pragma unroll
        for (int kt = 0; kt < 8; kt++) w1[kt] = *(const bf16x8*)(wp + kt * 32);
    }
    __syncthreads();

    // L1 GEMM K=256
    f32x4 acc[2];
    acc[0] = (f32x4){0.f,0.f,0.f,0.f}; acc[1] = (f32x4){0.f,0.f,0.f,0.f};
    #pragma unroll
    for (int kt = 0; kt < 8; kt++) {
        #pragma unroll
        for (int mt = 0; mt < 2; mt++) {
            int row = mt * 16 + row16;
            bf16x8 af = ((const bf16x8*)A)[row * 32 + ((kt * 4 + kg) ^ (row & 7))];
            acc[mt] = __builtin_amdgcn_mfma_f32_16x16x32_bf16(w1[kt], af, acc[mt], 0, 0, 0);
        }
    }

    float4 b1v = *(const float4*)(bn1 + n0);
    bf16x8 w2[4];
    {
        const short* wp = Wn2T + (wv * 16 + row16) * 128 + kg * 8;
        #pragma unroll
        for (int kt = 0; kt < 4; kt++) w2[kt] = *(const bf16x8*)(wp + kt * 32);
    }

    #pragma unroll
    for (int mt = 0; mt < 2; mt++) {
        int row = mt * 16 + row16;
        float v[4];
        #pragma unroll
        for (int r = 0; r < 4; r++) {
            float u = acc[mt][r] + b1v[r];
            v[r] = u > 0.f ? u : 0.f;
        }
        int G = (n0 >> 3) ^ (row & 7);
        *(uint2*)((char*)A2 + row * 256 + G * 16 + (n0 & 7) * 2) = (uint2){ pk2(v[0], v[1]), pk2(v[2], v[3]) };
    }
    __syncthreads();

    // L2 GEMM K=128, direct stores
    f32x4 acc2[2];
    acc2[0] = (f32x4){0.f,0.f,0.f,0.f}; acc2[1] = (f32x4){0.f,0.f,0.f,0.f};
    #pragma unroll
    for (int kt = 0; kt < 4; kt++) {
        #pragma unroll
        for (int mt = 0; mt < 2; mt++) {
            int row = mt * 16 + row16;
            bf16x8 hf = *(const bf16x8*)((const char*)A2 + row * 256 + (((kt * 4 + kg) ^ (row & 7)) * 16));
            acc2[mt] = __builtin_amdgcn_mfma_f32_16x16x32_bf16(w2[kt], hf, acc2[mt], 0, 0, 0);
        }
    }
    float4 b2v = *(const float4*)(bn2 + n0);
    #pragma unroll
    for (int mt = 0; mt < 2; mt++) {
        int node = nbase + mt * 16 + row16;
        if (node < Nn) {
            float4 ov;
            ov.x = acc2[mt][0] + b2v.x;
            ov.y = acc2[mt][1] + b2v.y;
            ov.z = acc2[mt][2] + b2v.z;
            ov.w = acc2[mt][3] + b2v.w;
            *(float4*)(xout + ((size_t)b * Nn + node) * Hd + n0) = ov;
        }
    }
}

extern "C" void kernel_launch(void* const* d_in, const int* in_sizes, int n_in,
                              void* d_out, int out_size, void* d_ws, size_t ws_size,
                              hipStream_t stream) {
    const float* x   = (const float*)d_in[0];
    const int*   ei  = (const int*)d_in[1];
    const float* ea  = (const float*)d_in[2];
    const float* We1 = (const float*)d_in[3];
    const float* be1 = (const float*)d_in[4];
    const float* We2 = (const float*)d_in[5];
    const float* be2 = (const float*)d_in[6];
    const float* Wn1 = (const float*)d_in[7];
    const float* bn1 = (const float*)d_in[8];
    const float* Wn2 = (const float*)d_in[9];
    const float* bn2 = (const float*)d_in[10];

    float* xout  = (float*)d_out;
    float* e_out = xout + (size_t)Bb * Nn * Hd;     // outputs: x_out, then e

    short* wbuf  = (short*)d_ws;                    // 114688 shorts
    short* xa    = wbuf + 114688;                   // NROWS*128 bf16
    short* xb    = xa + (size_t)NROWS * Hd;
    int*   cnt   = (int*)(xb + (size_t)NROWS * Hd);
    int*   cur   = cnt + Nn;
    int*   rp    = cur + Nn;                        // Nn+1
    int*   part  = rp + Nn + 1;                     // 256
    int*   elist = part + 256;                      // Ee

    hipMemsetAsync(cnt, 0, Nn * sizeof(int), stream);
    prep_weights<<<448, 256, 0, stream>>>(We1, We2, Wn1, Wn2, wbuf);
    hist_kernel<<<(Ee + 255) / 256, 256, 0, stream>>>(ei, cnt);
    scan1<<<196, 256, 0, stream>>>(cnt, cur, part);
    scan2<<<1, 64, 0, stream>>>(part);
    scan3<<<196, 256, 0, stream>>>(cur, part, rp);
    scatter_k<<<(Ee + 255) / 256, 256, 0, stream>>>(ei, cur, elist);

    node_pre<<<NROWS / 32, 256, 0, stream>>>(x, wbuf, xa, xb);

    edge_mlp<<<Bb * (Ee / 64), 512, 0, stream>>>(
        ea, ei, xa, xb, wbuf + 32768, be1, wbuf + 49152, be2, e_out);

    node_mlp<<<Bb * ((Nn + 31) / 32), 512, 0, stream>>>(
        x, e_out, rp, elist, wbuf + 65536, bn1, wbuf + 98304, bn2, xout);
}